// Round 9
// baseline (1653.842 us; speedup 1.0000x reference)
//
#include <hip/hip_runtime.h>
#include <stdint.h>

#define TOK 147456   // 16*96*96
#define CCH 512

typedef __attribute__((ext_vector_type(8))) short short8;
typedef __attribute__((ext_vector_type(4))) float f32x4;

struct alignas(8) US4 { unsigned short a, b, c, d; };

typedef __attribute__((address_space(3))) void lds_void;
typedef const __attribute__((address_space(1))) void gbl_void;

__device__ inline void gload16(const void* g, void* l) {
    __builtin_amdgcn_global_load_lds((gbl_void*)g, (lds_void*)l, 16, 0, 0);
}

__device__ inline unsigned short f2bf(float f) {
    union { float f; unsigned u; } v{f};
    unsigned r = v.u + 0x7fffu + ((v.u >> 16) & 1u);
    return (unsigned short)(r >> 16);
}
__device__ inline float bf2f(unsigned short h) {
    union { unsigned u; float f; } v; v.u = ((unsigned)h) << 16; return v.f;
}
__device__ inline float frcp(float x) {
    float r; asm("v_rcp_f32 %0, %1" : "=v"(r) : "v"(x)); return r;
}

// ---------------- weight transpose + cast:  in (K x N) f32 -> out (N x K) bf16
__global__ void wprep(const float* __restrict__ in, unsigned short* __restrict__ out,
                      int K, int N) {
    int idx = blockIdx.x * 256 + threadIdx.x;
    if (idx >= K * N) return;
    int k = idx / N, n = idx % N;
    out[(size_t)n * K + k] = f2bf(in[idx]);
}

// ---------------- rel_bias -> dense (16,48,48) f32 table, padded with -1e9
__global__ void biasprep(const float* __restrict__ rb, float* __restrict__ bb) {
    int idx = blockIdx.x * 256 + threadIdx.x;
    if (idx >= 16 * 48 * 48) return;
    int h = idx / 2304, rem = idx % 2304, r = rem / 48, c = rem % 48;
    float v = -1e9f;
    if (r < 36 && c < 36) {
        int dy = r / 6 - c / 6 + 5;
        int dx = r % 6 - c % 6 + 5;
        v = rb[(dy * 11 + dx) * 16 + h];
    }
    bb[idx] = v;
}

// ---------------- LayerNorm over C=512 (f32 input), one wave per token, out bf16
__global__ __launch_bounds__(256) void ln_k(const float* __restrict__ x,
                                            const float* __restrict__ g,
                                            const float* __restrict__ b,
                                            unsigned short* __restrict__ out, int ntok) {
    int lane = threadIdx.x & 63;
    int tok = blockIdx.x * 4 + (threadIdx.x >> 6);
    if (tok >= ntok) return;
    const float4* xr = (const float4*)(x + (size_t)tok * CCH);
    float4 v0 = xr[lane], v1 = xr[lane + 64];
    float s  = v0.x + v0.y + v0.z + v0.w + v1.x + v1.y + v1.z + v1.w;
    float s2 = v0.x*v0.x + v0.y*v0.y + v0.z*v0.z + v0.w*v0.w
             + v1.x*v1.x + v1.y*v1.y + v1.z*v1.z + v1.w*v1.w;
#pragma unroll
    for (int off = 32; off; off >>= 1) { s += __shfl_xor(s, off); s2 += __shfl_xor(s2, off); }
    float mean = s * (1.f / 512.f);
    float var  = s2 * (1.f / 512.f) - mean * mean;
    float inv  = rsqrtf(var + 1e-5f);
    const float4* gp = (const float4*)g;
    const float4* bp = (const float4*)b;
    float4 g0 = gp[lane], g1 = gp[lane + 64], b0 = bp[lane], b1 = bp[lane + 64];
    US4 o0, o1;
    o0.a = f2bf((v0.x - mean) * inv * g0.x + b0.x);
    o0.b = f2bf((v0.y - mean) * inv * g0.y + b0.y);
    o0.c = f2bf((v0.z - mean) * inv * g0.z + b0.z);
    o0.d = f2bf((v0.w - mean) * inv * g0.w + b0.w);
    o1.a = f2bf((v1.x - mean) * inv * g1.x + b1.x);
    o1.b = f2bf((v1.y - mean) * inv * g1.y + b1.y);
    o1.c = f2bf((v1.z - mean) * inv * g1.z + b1.z);
    o1.d = f2bf((v1.w - mean) * inv * g1.w + b1.w);
    unsigned short* op = out + (size_t)tok * CCH;
    *(US4*)(op + 4 * lane)       = o0;
    *(US4*)(op + 256 + 4 * lane) = o1;
}

// ---------------- LayerNorm over C=512 (bf16 input), one wave per token, out bf16
__global__ __launch_bounds__(256) void ln_bf(const unsigned short* __restrict__ x,
                                             const float* __restrict__ g,
                                             const float* __restrict__ b,
                                             unsigned short* __restrict__ out, int ntok) {
    int lane = threadIdx.x & 63;
    int tok = blockIdx.x * 4 + (threadIdx.x >> 6);
    if (tok >= ntok) return;
    short8 v = *(const short8*)(x + (size_t)tok * CCH + lane * 8);
    float f[8];
#pragma unroll
    for (int j = 0; j < 8; ++j) f[j] = bf2f((unsigned short)v[j]);
    float s = 0.f, s2 = 0.f;
#pragma unroll
    for (int j = 0; j < 8; ++j) { s += f[j]; s2 += f[j] * f[j]; }
#pragma unroll
    for (int off = 32; off; off >>= 1) { s += __shfl_xor(s, off); s2 += __shfl_xor(s2, off); }
    float mean = s * (1.f / 512.f);
    float var  = s2 * (1.f / 512.f) - mean * mean;
    float inv  = rsqrtf(var + 1e-5f);
    const float4* gp = (const float4*)g + lane * 2;
    const float4* bp = (const float4*)b + lane * 2;
    float4 g0 = gp[0], g1 = gp[1], b0 = bp[0], b1 = bp[1];
    float gg[8] = {g0.x, g0.y, g0.z, g0.w, g1.x, g1.y, g1.z, g1.w};
    float bb[8] = {b0.x, b0.y, b0.z, b0.w, b1.x, b1.y, b1.z, b1.w};
    short8 o;
#pragma unroll
    for (int j = 0; j < 8; ++j) o[j] = (short)f2bf((f[j] - mean) * inv * gg[j] + bb[j]);
    *(short8*)(out + (size_t)tok * CCH + lane * 8) = o;
}

// ---------------- MFMA windowed attention: one wave per (window, head)
__global__ __launch_bounds__(256) void attn_mfma(const unsigned short* __restrict__ qkv,
                                                 const float* __restrict__ biasb,
                                                 unsigned short* __restrict__ o) {
    __shared__ __align__(16) unsigned short p_lds[4][48 * 64];
    __shared__ __align__(16) unsigned short v_lds[4][32 * 64];

    int tid  = threadIdx.x;
    int wv   = tid >> 6;
    int lane = tid & 63;
    int l15  = lane & 15;
    int g    = lane >> 4;

    int wid = blockIdx.x * 4 + wv;
    int h   = wid & 15;
    int win = wid >> 4;
    int img  = win >> 8;
    int wrow = (win >> 4) & 15;
    int wcol = win & 15;
    int tok_base = (img * 96 + wrow * 6) * 96 + wcol * 6;

    unsigned short* pw = p_lds[wv];
    unsigned short* vw = v_lds[wv];

    #define TOKOF(r) (tok_base + (r) + 90 * ((r) / 6))

    short8 z8 = {};
    for (int e = lane; e < 224; e += 64) {
        if (e < 128) {
            int ch = e >> 2, kst = 32 + (e & 3) * 8;
            *(short8*)(vw + ch * 64 + (kst ^ ((ch & 7) << 3))) = z8;
        } else {
            int ee = e - 128; int q = ee >> 1, kst = 48 + (ee & 1) * 8;
            *(short8*)(pw + q * 64 + (kst ^ ((q & 7) << 3))) = z8;
        }
    }

    for (int e = lane; e < 144; e += 64) {
        int r = e >> 2, c0 = (e & 3) * 8;
        short8 vv = *(const short8*)(qkv + (size_t)TOKOF(r) * 1536 + 1024 + h * 32 + c0);
#pragma unroll
        for (int j = 0; j < 8; ++j) {
            int ch = c0 + j;
            vw[ch * 64 + (r ^ ((ch & 7) << 3))] = (unsigned short)vv[j];
        }
    }

    short8 qf[3], kf[3];
#pragma unroll
    for (int t = 0; t < 3; ++t) {
        int r = t * 16 + l15;
        if (r < 36) {
            size_t ba = (size_t)TOKOF(r) * 1536 + h * 32 + g * 8;
            qf[t] = *(const short8*)(qkv + ba);
            kf[t] = *(const short8*)(qkv + ba + 512);
        } else { qf[t] = z8; kf[t] = z8; }
    }

    f32x4 s[3][3] = {};
#pragma unroll
    for (int mt = 0; mt < 3; ++mt)
#pragma unroll
        for (int nt = 0; nt < 3; ++nt)
            s[mt][nt] = __builtin_amdgcn_mfma_f32_16x16x32_bf16(qf[mt], kf[nt], s[mt][nt], 0, 0, 0);

    const float SCALE = 0.17677669529663687f;  // 1/sqrt(32)
    const float* bh = biasb + h * 2304;
#pragma unroll
    for (int mt = 0; mt < 3; ++mt) {
#pragma unroll
        for (int r = 0; r < 4; ++r) {
            int row = mt * 16 + g * 4 + r;
            const float* bb = bh + row * 48 + l15;
            float v0 = fmaf(s[mt][0][r], SCALE, bb[0]);
            float v1 = fmaf(s[mt][1][r], SCALE, bb[16]);
            float v2 = fmaf(s[mt][2][r], SCALE, bb[32]);
            float m = fmaxf(fmaxf(v0, v1), v2);
#pragma unroll
            for (int off = 1; off < 16; off <<= 1) m = fmaxf(m, __shfl_xor(m, off));
            float e0 = __expf(v0 - m), e1 = __expf(v1 - m), e2 = __expf(v2 - m);
            float sm = e0 + e1 + e2;
#pragma unroll
            for (int off = 1; off < 16; off <<= 1) sm += __shfl_xor(sm, off);
            float inv = 1.f / sm;
            int sw = (row & 7) << 3;
            unsigned short* pr = pw + row * 64;
            pr[(l15)      ^ sw] = f2bf(e0 * inv);
            pr[(16 + l15) ^ sw] = f2bf(e1 * inv);
            pr[(32 + l15) ^ sw] = f2bf(e2 * inv);
        }
    }

    f32x4 oacc[3][2] = {};
#pragma unroll
    for (int ks = 0; ks < 2; ++ks) {
        int kst = ks * 32 + g * 8;
        short8 bfr[2];
#pragma unroll
        for (int nt = 0; nt < 2; ++nt) {
            int c = nt * 16 + l15;
            bfr[nt] = *(const short8*)(vw + c * 64 + (kst ^ ((c & 7) << 3)));
        }
#pragma unroll
        for (int mt = 0; mt < 3; ++mt) {
            int q = mt * 16 + l15;
            short8 pa = *(const short8*)(pw + q * 64 + (kst ^ ((q & 7) << 3)));
#pragma unroll
            for (int nt = 0; nt < 2; ++nt)
                oacc[mt][nt] = __builtin_amdgcn_mfma_f32_16x16x32_bf16(pa, bfr[nt], oacc[mt][nt], 0, 0, 0);
        }
    }

#pragma unroll
    for (int mt = 0; mt < 3; ++mt) {
#pragma unroll
        for (int r = 0; r < 4; ++r) {
            int q = mt * 16 + g * 4 + r;
            if (q < 36) {
                size_t rb = (size_t)TOKOF(q) * 512 + h * 32;
#pragma unroll
                for (int nt = 0; nt < 2; ++nt)
                    o[rb + nt * 16 + l15] = f2bf(oacc[mt][nt][r]);
            }
        }
    }
    #undef TOKOF
}

// ---------------- 128x128-tile bf16 MFMA GEMM (m97-replica), 4 blocks/CU
// 256 thr = 4 waves (2M x 2N), wave 64x64 (acc 64 VGPR, total ~115 <= 128).
// LDS: ring-2 x 16KB (A 8KB @0, B 8KB @8192) = 32KB/block -> 4 blocks/CU,
// i.e. 4 INDEPENDENT barrier domains (the m97/m114 overlap mechanism).
// Per K-tile: {STAGE(t+1 -> other slot); vmcnt(4) [counted: waits tile t only];
//   barrier; 4+4 ds_read; lgkm(0); 16 MFMA; barrier}.
// Pair-interleave XOR swizzle (R5-proven, 2-way banks = free):
//   (row,granule g) -> line=row>>1, pos=(g+(row&1)*4)^(line&7), byte=line*128+pos*16
// EPI: 0 = bf16; 1 = bf16 + bias; 2 = bf16 gelu(x+bias); 3 = f32 (x+bias+resid_bf16)
template <int EPI>
__global__ __launch_bounds__(256, 4) void gemm8(const unsigned short* __restrict__ A,
                                                const unsigned short* __restrict__ Bt,
                                                int M, int N, int K,
                                                const float* __restrict__ bias,
                                                const unsigned short* __restrict__ resid,
                                                void* __restrict__ Cout) {
    extern __shared__ char lds[];
    int tid = threadIdx.x;
    int w = tid >> 6, lane = tid & 63;
    int l15 = lane & 15, grp = lane >> 4;
    int wm = w >> 1, wn = w & 1;            // 2M x 2N, wave tile 64x64

    int nbn = N >> 7;                        // N-tiles of 128
    int nwg = gridDim.x;
    int q = nwg >> 3, r = nwg & 7;
    int xcd = blockIdx.x & 7, pos_ = blockIdx.x >> 3;
    int wgid = (xcd < r ? xcd * (q + 1) : r * (q + 1) + (xcd - r) * q) + pos_;
    int bm = wgid / nbn, bn = wgid % nbn;    // M-major: consecutive blocks share A

    int NT = K >> 5;

    // staging: dest linear tid*16 (+4096 for j=1); source inverse-swizzled
    int u = (tid & 7) ^ ((tid >> 3) & 7);
    int srow = ((tid >> 3) << 1) + (u >> 2);         // 0..63
    int scol = (u & 3) * 8;
    const unsigned short* aSrc = A  + ((size_t)bm * 128 + srow) * (size_t)K + scol;
    const unsigned short* bSrc = Bt + ((size_t)bn * 128 + srow) * (size_t)K + scol;

    #define STAGE(t, sp) do { size_t ko_ = (size_t)(t) * 32; \
        gload16(aSrc + ko_,                  (sp) + tid * 16); \
        gload16(aSrc + ko_ + (size_t)64 * K, (sp) + 4096  + tid * 16); \
        gload16(bSrc + ko_,                  (sp) + 8192  + tid * 16); \
        gload16(bSrc + ko_ + (size_t)64 * K, (sp) + 12288 + tid * 16); } while (0)

    // fragment read addressing (pair-interleave XOR swizzle)
    int rpos = (grp + (l15 & 1) * 4) ^ ((l15 >> 1) & 7);
    int aRd = (wm * 32 + (l15 >> 1)) * 128 + rpos * 16;            // + mi*1024
    int bRd = 8192 + (wn * 32 + (l15 >> 1)) * 128 + rpos * 16;     // + ni*1024

    f32x4 acc[4][4] = {};

    char* s0 = lds;
    char* s1 = lds + 16384;
    STAGE(0, s0);

    for (int t = 0; t < NT; ++t) {
        char* cur = (t & 1) ? s1 : s0;
        char* nxt = (t & 1) ? s0 : s1;
        if (t + 1 < NT) {
            STAGE(t + 1, nxt);                                 // into slot whose readers
            asm volatile("s_waitcnt vmcnt(4)" ::: "memory");   // finished last iter
        } else {
            asm volatile("s_waitcnt vmcnt(0)" ::: "memory");
        }
        __builtin_amdgcn_s_barrier();        // tile t visible to all 4 waves
        short8 af[4], bf[4];
#pragma unroll
        for (int m = 0; m < 4; ++m) af[m] = *(const short8*)(cur + aRd + m * 1024);
#pragma unroll
        for (int n = 0; n < 4; ++n) bf[n] = *(const short8*)(cur + bRd + n * 1024);
        asm volatile("s_waitcnt lgkmcnt(0)" ::: "memory");
        __builtin_amdgcn_sched_barrier(0);
        __builtin_amdgcn_s_setprio(1);
#pragma unroll
        for (int m = 0; m < 4; ++m)
#pragma unroll
            for (int n = 0; n < 4; ++n)
                acc[m][n] = __builtin_amdgcn_mfma_f32_16x16x32_bf16(af[m], bf[n], acc[m][n], 0, 0, 0);
        __builtin_amdgcn_s_setprio(0);
        __builtin_amdgcn_s_barrier();        // reads of slot done -> restage safe
    }
    #undef STAGE

    // ---- epilogue (64 values/thread)
    int row0 = bm * 128 + wm * 64 + grp * 4;
    int col0 = bn * 128 + wn * 64 + l15;
#pragma unroll
    for (int m = 0; m < 4; ++m) {
#pragma unroll
        for (int n = 0; n < 4; ++n) {
            int col = col0 + n * 16;
            float bv = (EPI == 0) ? 0.f : bias[col];
#pragma unroll
            for (int r2 = 0; r2 < 4; ++r2) {
                int row = row0 + m * 16 + r2;
                size_t idx = (size_t)row * N + col;
                float val = acc[m][n][r2] + bv;
                if (EPI == 0) {
                    ((unsigned short*)Cout)[idx] = f2bf(val);
                } else if (EPI == 1) {
                    ((unsigned short*)Cout)[idx] = f2bf(val);
                } else if (EPI == 2) {
                    // gelu = x - x/(e^{z}+1),  z = 1.5957691*(x + 0.044715 x^3)
                    float t1 = val * val;
                    float t2 = fmaf(t1, 0.0713548163f, 1.5957691216f);
                    float z  = val * t2;
                    float e  = __expf(z);
                    float rr = frcp(e + 1.f);
                    float ge = val - val * rr;
                    ((unsigned short*)Cout)[idx] = f2bf(ge);
                } else {
                    ((float*)Cout)[idx] = val + bf2f(resid[idx]);
                }
            }
        }
    }
}

extern "C" void kernel_launch(void* const* d_in, const int* in_sizes, int n_in,
                              void* d_out, int out_size, void* d_ws, size_t ws_size,
                              hipStream_t stream) {
    const float* x       = (const float*)d_in[0];
    const float* w_qkv   = (const float*)d_in[1];
    const float* w_proj  = (const float*)d_in[2];
    const float* b_proj  = (const float*)d_in[3];
    const float* relb    = (const float*)d_in[4];
    const float* ln1g    = (const float*)d_in[5];
    const float* ln1b    = (const float*)d_in[6];
    const float* ln2g    = (const float*)d_in[7];
    const float* ln2b    = (const float*)d_in[8];
    const float* w_fc1   = (const float*)d_in[9];
    const float* b_fc1   = (const float*)d_in[10];
    const float* w_fc2   = (const float*)d_in[11];
    const float* b_fc2   = (const float*)d_in[12];
    float* out = (float*)d_out;

    hipFuncSetAttribute(reinterpret_cast<const void*>(&gemm8<0>),
                        hipFuncAttributeMaxDynamicSharedMemorySize, 32768);
    hipFuncSetAttribute(reinterpret_cast<const void*>(&gemm8<1>),
                        hipFuncAttributeMaxDynamicSharedMemorySize, 32768);
    hipFuncSetAttribute(reinterpret_cast<const void*>(&gemm8<2>),
                        hipFuncAttributeMaxDynamicSharedMemorySize, 32768);
    hipFuncSetAttribute(reinterpret_cast<const void*>(&gemm8<3>),
                        hipFuncAttributeMaxDynamicSharedMemorySize, 32768);

    char* w = (char*)d_ws;
    unsigned short* wT_qkv  = (unsigned short*)w; w += (size_t)1536 * 512 * 2;
    unsigned short* wT_proj = (unsigned short*)w; w += (size_t)512  * 512 * 2;
    unsigned short* wT_fc1  = (unsigned short*)w; w += (size_t)2048 * 512 * 2;
    unsigned short* wT_fc2  = (unsigned short*)w; w += (size_t)512  * 2048 * 2;
    float* biasb            = (float*)w;          w += (size_t)16 * 48 * 48 * 4;
    size_t wbytes = (size_t)(w - (char*)d_ws);

    int nchunk = 16;
    for (int c = 1; c <= 16; c *= 2) {
        size_t tokc = TOK / c;
        if (wbytes + tokc * 6144 <= ws_size) { nchunk = c; break; }
    }
    size_t tokc = TOK / nchunk;
    unsigned short* buf1 = (unsigned short*)w;
    unsigned short* buf2 = (unsigned short*)(w + tokc * 1024);
    unsigned short* buf3 = (unsigned short*)(w + tokc * 5120);

    wprep<<<(512 * 1536 + 255) / 256, 256, 0, stream>>>(w_qkv,  wT_qkv,  512, 1536);
    wprep<<<(512 * 512  + 255) / 256, 256, 0, stream>>>(w_proj, wT_proj, 512, 512);
    wprep<<<(512 * 2048 + 255) / 256, 256, 0, stream>>>(w_fc1,  wT_fc1,  512, 2048);
    wprep<<<(2048 * 512 + 255) / 256, 256, 0, stream>>>(w_fc2,  wT_fc2,  2048, 512);
    biasprep<<<(16 * 48 * 48 + 255) / 256, 256, 0, stream>>>(relb, biasb);

    int Mc = (int)tokc;
    int gm = Mc / 128;
    int imgs = Mc / 9216;

    for (int c = 0; c < nchunk; ++c) {
        size_t toff = (size_t)c * tokc;
        const float* xc = x + toff * CCH;
        float* outc = out + toff * CCH;

        ln_k<<<Mc / 4, 256, 0, stream>>>(xc, ln1g, ln1b, buf1, Mc);
        gemm8<0><<<gm * 12, 256, 32768, stream>>>(buf1, wT_qkv, Mc, 1536, 512,
                                                  nullptr, nullptr, buf2);
        attn_mfma<<<imgs * 1024, 256, 0, stream>>>(buf2, biasb, buf1);
        gemm8<1><<<gm * 4, 256, 32768, stream>>>(buf1, wT_proj, Mc, 512, 512,
                                                 b_proj, nullptr, buf3);
        ln_bf<<<Mc / 4, 256, 0, stream>>>(buf3, ln2g, ln2b, buf1, Mc);
        gemm8<2><<<gm * 16, 256, 32768, stream>>>(buf1, wT_fc1, Mc, 2048, 512,
                                                  b_fc1, nullptr, buf2);
        gemm8<3><<<gm * 4, 256, 32768, stream>>>(buf2, wT_fc2, Mc, 512, 2048,
                                                 b_fc2, buf3, outc);
    }
}

// Round 10
// 1497.705 us; speedup vs baseline: 1.1043x; 1.1043x over previous
//
#include <hip/hip_runtime.h>
#include <stdint.h>

#define TOK 147456   // 16*96*96
#define CCH 512

typedef __attribute__((ext_vector_type(8))) short short8;
typedef __attribute__((ext_vector_type(4))) float f32x4;

struct alignas(8) US4 { unsigned short a, b, c, d; };

typedef __attribute__((address_space(3))) void lds_void;
typedef const __attribute__((address_space(1))) void gbl_void;

__device__ inline void gload16(const void* g, void* l) {
    __builtin_amdgcn_global_load_lds((gbl_void*)g, (lds_void*)l, 16, 0, 0);
}

__device__ inline unsigned short f2bf(float f) {
    union { float f; unsigned u; } v{f};
    unsigned r = v.u + 0x7fffu + ((v.u >> 16) & 1u);
    return (unsigned short)(r >> 16);
}
__device__ inline float bf2f(unsigned short h) {
    union { unsigned u; float f; } v; v.u = ((unsigned)h) << 16; return v.f;
}
__device__ inline float frcp(float x) {
    float r; asm("v_rcp_f32 %0, %1" : "=v"(r) : "v"(x)); return r;
}

// ---------------- weight transpose + cast:  in (K x N) f32 -> out (N x K) bf16
__global__ void wprep(const float* __restrict__ in, unsigned short* __restrict__ out,
                      int K, int N) {
    int idx = blockIdx.x * 256 + threadIdx.x;
    if (idx >= K * N) return;
    int k = idx / N, n = idx % N;
    out[(size_t)n * K + k] = f2bf(in[idx]);
}

// ---------------- rel_bias -> dense (16,48,48) f32 table, padded with -1e9
__global__ void biasprep(const float* __restrict__ rb, float* __restrict__ bb) {
    int idx = blockIdx.x * 256 + threadIdx.x;
    if (idx >= 16 * 48 * 48) return;
    int h = idx / 2304, rem = idx % 2304, r = rem / 48, c = rem % 48;
    float v = -1e9f;
    if (r < 36 && c < 36) {
        int dy = r / 6 - c / 6 + 5;
        int dx = r % 6 - c % 6 + 5;
        v = rb[(dy * 11 + dx) * 16 + h];
    }
    bb[idx] = v;
}

// ---------------- LayerNorm over C=512 (f32 input), one wave per token, out bf16
__global__ __launch_bounds__(256) void ln_k(const float* __restrict__ x,
                                            const float* __restrict__ g,
                                            const float* __restrict__ b,
                                            unsigned short* __restrict__ out, int ntok) {
    int lane = threadIdx.x & 63;
    int tok = blockIdx.x * 4 + (threadIdx.x >> 6);
    if (tok >= ntok) return;
    const float4* xr = (const float4*)(x + (size_t)tok * CCH);
    float4 v0 = xr[lane], v1 = xr[lane + 64];
    float s  = v0.x + v0.y + v0.z + v0.w + v1.x + v1.y + v1.z + v1.w;
    float s2 = v0.x*v0.x + v0.y*v0.y + v0.z*v0.z + v0.w*v0.w
             + v1.x*v1.x + v1.y*v1.y + v1.z*v1.z + v1.w*v1.w;
#pragma unroll
    for (int off = 32; off; off >>= 1) { s += __shfl_xor(s, off); s2 += __shfl_xor(s2, off); }
    float mean = s * (1.f / 512.f);
    float var  = s2 * (1.f / 512.f) - mean * mean;
    float inv  = rsqrtf(var + 1e-5f);
    const float4* gp = (const float4*)g;
    const float4* bp = (const float4*)b;
    float4 g0 = gp[lane], g1 = gp[lane + 64], b0 = bp[lane], b1 = bp[lane + 64];
    US4 o0, o1;
    o0.a = f2bf((v0.x - mean) * inv * g0.x + b0.x);
    o0.b = f2bf((v0.y - mean) * inv * g0.y + b0.y);
    o0.c = f2bf((v0.z - mean) * inv * g0.z + b0.z);
    o0.d = f2bf((v0.w - mean) * inv * g0.w + b0.w);
    o1.a = f2bf((v1.x - mean) * inv * g1.x + b1.x);
    o1.b = f2bf((v1.y - mean) * inv * g1.y + b1.y);
    o1.c = f2bf((v1.z - mean) * inv * g1.z + b1.z);
    o1.d = f2bf((v1.w - mean) * inv * g1.w + b1.w);
    unsigned short* op = out + (size_t)tok * CCH;
    *(US4*)(op + 4 * lane)       = o0;
    *(US4*)(op + 256 + 4 * lane) = o1;
}

// ---------------- LayerNorm over C=512 (bf16 input), one wave per token, out bf16
__global__ __launch_bounds__(256) void ln_bf(const unsigned short* __restrict__ x,
                                             const float* __restrict__ g,
                                             const float* __restrict__ b,
                                             unsigned short* __restrict__ out, int ntok) {
    int lane = threadIdx.x & 63;
    int tok = blockIdx.x * 4 + (threadIdx.x >> 6);
    if (tok >= ntok) return;
    short8 v = *(const short8*)(x + (size_t)tok * CCH + lane * 8);
    float f[8];
#pragma unroll
    for (int j = 0; j < 8; ++j) f[j] = bf2f((unsigned short)v[j]);
    float s = 0.f, s2 = 0.f;
#pragma unroll
    for (int j = 0; j < 8; ++j) { s += f[j]; s2 += f[j] * f[j]; }
#pragma unroll
    for (int off = 32; off; off >>= 1) { s += __shfl_xor(s, off); s2 += __shfl_xor(s2, off); }
    float mean = s * (1.f / 512.f);
    float var  = s2 * (1.f / 512.f) - mean * mean;
    float inv  = rsqrtf(var + 1e-5f);
    const float4* gp = (const float4*)g + lane * 2;
    const float4* bp = (const float4*)b + lane * 2;
    float4 g0 = gp[0], g1 = gp[1], b0 = bp[0], b1 = bp[1];
    float gg[8] = {g0.x, g0.y, g0.z, g0.w, g1.x, g1.y, g1.z, g1.w};
    float bb[8] = {b0.x, b0.y, b0.z, b0.w, b1.x, b1.y, b1.z, b1.w};
    short8 o;
#pragma unroll
    for (int j = 0; j < 8; ++j) o[j] = (short)f2bf((f[j] - mean) * inv * gg[j] + bb[j]);
    *(short8*)(out + (size_t)tok * CCH + lane * 8) = o;
}

// ---------------- MFMA windowed attention: one wave per (window, head)
__global__ __launch_bounds__(256) void attn_mfma(const unsigned short* __restrict__ qkv,
                                                 const float* __restrict__ biasb,
                                                 unsigned short* __restrict__ o) {
    __shared__ __align__(16) unsigned short p_lds[4][48 * 64];
    __shared__ __align__(16) unsigned short v_lds[4][32 * 64];

    int tid  = threadIdx.x;
    int wv   = tid >> 6;
    int lane = tid & 63;
    int l15  = lane & 15;
    int g    = lane >> 4;

    int wid = blockIdx.x * 4 + wv;
    int h   = wid & 15;
    int win = wid >> 4;
    int img  = win >> 8;
    int wrow = (win >> 4) & 15;
    int wcol = win & 15;
    int tok_base = (img * 96 + wrow * 6) * 96 + wcol * 6;

    unsigned short* pw = p_lds[wv];
    unsigned short* vw = v_lds[wv];

    #define TOKOF(r) (tok_base + (r) + 90 * ((r) / 6))

    short8 z8 = {};
    for (int e = lane; e < 224; e += 64) {
        if (e < 128) {
            int ch = e >> 2, kst = 32 + (e & 3) * 8;
            *(short8*)(vw + ch * 64 + (kst ^ ((ch & 7) << 3))) = z8;
        } else {
            int ee = e - 128; int q = ee >> 1, kst = 48 + (ee & 1) * 8;
            *(short8*)(pw + q * 64 + (kst ^ ((q & 7) << 3))) = z8;
        }
    }

    for (int e = lane; e < 144; e += 64) {
        int r = e >> 2, c0 = (e & 3) * 8;
        short8 vv = *(const short8*)(qkv + (size_t)TOKOF(r) * 1536 + 1024 + h * 32 + c0);
#pragma unroll
        for (int j = 0; j < 8; ++j) {
            int ch = c0 + j;
            vw[ch * 64 + (r ^ ((ch & 7) << 3))] = (unsigned short)vv[j];
        }
    }

    short8 qf[3], kf[3];
#pragma unroll
    for (int t = 0; t < 3; ++t) {
        int r = t * 16 + l15;
        if (r < 36) {
            size_t ba = (size_t)TOKOF(r) * 1536 + h * 32 + g * 8;
            qf[t] = *(const short8*)(qkv + ba);
            kf[t] = *(const short8*)(qkv + ba + 512);
        } else { qf[t] = z8; kf[t] = z8; }
    }

    f32x4 s[3][3] = {};
#pragma unroll
    for (int mt = 0; mt < 3; ++mt)
#pragma unroll
        for (int nt = 0; nt < 3; ++nt)
            s[mt][nt] = __builtin_amdgcn_mfma_f32_16x16x32_bf16(qf[mt], kf[nt], s[mt][nt], 0, 0, 0);

    const float SCALE = 0.17677669529663687f;  // 1/sqrt(32)
    const float* bh = biasb + h * 2304;
#pragma unroll
    for (int mt = 0; mt < 3; ++mt) {
#pragma unroll
        for (int r = 0; r < 4; ++r) {
            int row = mt * 16 + g * 4 + r;
            const float* bb = bh + row * 48 + l15;
            float v0 = fmaf(s[mt][0][r], SCALE, bb[0]);
            float v1 = fmaf(s[mt][1][r], SCALE, bb[16]);
            float v2 = fmaf(s[mt][2][r], SCALE, bb[32]);
            float m = fmaxf(fmaxf(v0, v1), v2);
#pragma unroll
            for (int off = 1; off < 16; off <<= 1) m = fmaxf(m, __shfl_xor(m, off));
            float e0 = __expf(v0 - m), e1 = __expf(v1 - m), e2 = __expf(v2 - m);
            float sm = e0 + e1 + e2;
#pragma unroll
            for (int off = 1; off < 16; off <<= 1) sm += __shfl_xor(sm, off);
            float inv = 1.f / sm;
            int sw = (row & 7) << 3;
            unsigned short* pr = pw + row * 64;
            pr[(l15)      ^ sw] = f2bf(e0 * inv);
            pr[(16 + l15) ^ sw] = f2bf(e1 * inv);
            pr[(32 + l15) ^ sw] = f2bf(e2 * inv);
        }
    }

    f32x4 oacc[3][2] = {};
#pragma unroll
    for (int ks = 0; ks < 2; ++ks) {
        int kst = ks * 32 + g * 8;
        short8 bfr[2];
#pragma unroll
        for (int nt = 0; nt < 2; ++nt) {
            int c = nt * 16 + l15;
            bfr[nt] = *(const short8*)(vw + c * 64 + (kst ^ ((c & 7) << 3)));
        }
#pragma unroll
        for (int mt = 0; mt < 3; ++mt) {
            int q = mt * 16 + l15;
            short8 pa = *(const short8*)(pw + q * 64 + (kst ^ ((q & 7) << 3)));
#pragma unroll
            for (int nt = 0; nt < 2; ++nt)
                oacc[mt][nt] = __builtin_amdgcn_mfma_f32_16x16x32_bf16(pa, bfr[nt], oacc[mt][nt], 0, 0, 0);
        }
    }

#pragma unroll
    for (int mt = 0; mt < 3; ++mt) {
#pragma unroll
        for (int r = 0; r < 4; ++r) {
            int q = mt * 16 + g * 4 + r;
            if (q < 36) {
                size_t rb = (size_t)TOKOF(q) * 512 + h * 32;
#pragma unroll
                for (int nt = 0; nt < 2; ++nt)
                    o[rb + nt * 16 + l15] = f2bf(oacc[mt][nt][r]);
            }
        }
    }
    #undef TOKOF
}

// ---------------- 256x256-tile bf16 MFMA GEMM, 8-phase counted-vmcnt (m201/m248 port)
// 512 thr = 8 waves (2M x 4N), wave tile 128x64 (acc 128 VGPR).
// LDS 128KB: dbuf0 (K-tile a: A 32KB @0, B 32KB @32768), dbuf1 (K-tile b @65536).
// Iter = 2 K-tiles (BK=64 each). 8 phases/iter, each:
//   {ds_read 0-12 frags; stage 1 half-tile (2 gloads); barrier; lgkm(0);
//    setprio(1); 16 MFMA; setprio(0); barrier}
// Stage slots (ledger-verified): P1,P2 -> A-b(this iter); P3,P4 -> B-a';
//   P5,P6 -> A-a'; P7,P8 -> B-b'. vmcnt(4) ONLY at P4 & P8 (last iter P4: vmcnt(0)).
// Swizzle: LDS(row, pos) holds granule pos^(row&7); linear dest (rule 21),
//   inverse-swizzled global source; reads land 8 lanes/slot = b128 floor.
// EPI: 0 = bf16; 1 = bf16 + bias; 2 = bf16 gelu(x+bias); 3 = f32 (x+bias+resid_bf16)
template <int EPI>
__global__ __launch_bounds__(512, 1) void gemm8(const unsigned short* __restrict__ A,
                                                const unsigned short* __restrict__ Bt,
                                                int M, int N, int K,
                                                const float* __restrict__ bias,
                                                const unsigned short* __restrict__ resid,
                                                void* __restrict__ Cout) {
    extern __shared__ char lds[];
    int tid = threadIdx.x;
    int w = tid >> 6, lane = tid & 63;
    int l15 = lane & 15, grp = lane >> 4, l7 = l15 & 7;
    int wm = w >> 2, wn = w & 3;             // 2M x 4N, wave tile 128x64

    int nbn = N >> 8;
    int nwg = gridDim.x;
    int q = nwg >> 3, r = nwg & 7;
    int xcd = blockIdx.x & 7, pos_ = blockIdx.x >> 3;
    int wgid = (xcd < r ? xcd * (q + 1) : r * (q + 1) + (xcd - r) * q) + pos_;
    int bm = wgid / nbn, bn = wgid % nbn;

    int NI = K >> 7;                          // 128 K per iter (2 x BK=64)

    // staging: dest linear tid*16 (+8192 for j=1); source inverse-swizzled
    int trow = tid >> 3;                      // 0..63
    int sg = (tid & 7) ^ (trow & 7);
    const unsigned short* aBase = A  + ((size_t)bm * 256 + trow) * (size_t)K + sg * 8;
    const unsigned short* bBase = Bt + ((size_t)bn * 256 + trow) * (size_t)K + sg * 8;

    #define STG(base, rowOff, kt, dst) do { \
        gload16((base) + (size_t)(rowOff) * K + (kt),        lds + (dst) + tid * 16); \
        gload16((base) + (size_t)((rowOff) + 64) * K + (kt), lds + (dst) + 8192 + tid * 16); } while (0)

    // fragment read bases (pos = granule ^ (row&7); ks=1 -> addr ^ 64)
    int aR0 = wm * 16384 + l15 * 128 + ((grp ^ l7) << 4);
    int bR0 = 32768 + (wn >> 1) * 16384 + (wn & 1) * 8192 + l15 * 128 + ((grp ^ l7) << 4);

    f32x4 acc[8][4] = {};
    short8 Af[4][2], Bf[4][2];

    // prologue: B-a0(h0,h1), A-a0(h0,h1), B-b0(h0,h1)  [ledger slots P3..P8]
    STG(bBase, 0,   0,  32768);
    STG(bBase, 128, 0,  32768 + 16384);
    STG(aBase, 0,   0,  0);
    STG(aBase, 128, 0,  16384);
    STG(bBase, 0,   64, 65536 + 32768);
    STG(bBase, 128, 64, 65536 + 32768 + 16384);
    asm volatile("s_waitcnt vmcnt(4)" ::: "memory");
    __builtin_amdgcn_s_barrier();

    #define RDA(d, qm) do { int ab_ = (d) * 65536 + (qm) * 8192 + aR0; \
        _Pragma("unroll") for (int mi_ = 0; mi_ < 4; ++mi_) { \
            Af[mi_][0] = *(const short8*)(lds + ab_ + mi_ * 2048); \
            Af[mi_][1] = *(const short8*)(lds + ((ab_ + mi_ * 2048) ^ 64)); } } while (0)
    #define RDB(d, nh) do { int bb_ = (d) * 65536 + (nh) * 4096 + bR0; \
        _Pragma("unroll") for (int nj_ = 0; nj_ < 2; ++nj_) { \
            Bf[(nh) * 2 + nj_][0] = *(const short8*)(lds + bb_ + nj_ * 2048); \
            Bf[(nh) * 2 + nj_][1] = *(const short8*)(lds + ((bb_ + nj_ * 2048) ^ 64)); } } while (0)
    #define MFQ(qm, nh) do { \
        _Pragma("unroll") for (int mi_ = 0; mi_ < 4; ++mi_) \
        _Pragma("unroll") for (int nj_ = 0; nj_ < 2; ++nj_) \
        _Pragma("unroll") for (int ks_ = 0; ks_ < 2; ++ks_) \
            acc[(qm) * 4 + mi_][(nh) * 2 + nj_] = __builtin_amdgcn_mfma_f32_16x16x32_bf16( \
                Af[mi_][ks_], Bf[(nh) * 2 + nj_][ks_], acc[(qm) * 4 + mi_][(nh) * 2 + nj_], 0, 0, 0); } while (0)
    #define PH_PRE  do { __builtin_amdgcn_s_barrier(); \
        asm volatile("s_waitcnt lgkmcnt(0)" ::: "memory"); \
        __builtin_amdgcn_sched_barrier(0); \
        __builtin_amdgcn_s_setprio(1); } while (0)
    #define PH_POST do { __builtin_amdgcn_s_setprio(0); \
        __builtin_amdgcn_s_barrier(); } while (0)

    for (int i = 0; i < NI; ++i) {
        int tka = i << 7, tkb = tka + 64;
        bool pf = (i + 1 < NI);
        // P1: tile-a q0 reads; stage A-b h0 (this iter)
        RDA(0, 0); RDB(0, 0);
        STG(aBase, 0, tkb, 65536);
        PH_PRE; MFQ(0, 0); PH_POST;
        // P2: B n2-3; stage A-b h1
        RDB(0, 1);
        STG(aBase, 128, tkb, 65536 + 16384);
        PH_PRE; MFQ(0, 1); PH_POST;
        // P3: A m4-7; stage B-a' h0
        RDA(0, 1);
        if (pf) STG(bBase, 0, tka + 128, 32768);
        PH_PRE; MFQ(1, 0); PH_POST;
        // P4: no reads; stage B-a' h1; counted vmcnt
        if (pf) {
            STG(bBase, 128, tka + 128, 32768 + 16384);
            asm volatile("s_waitcnt vmcnt(4)" ::: "memory");
        } else {
            asm volatile("s_waitcnt vmcnt(0)" ::: "memory");
        }
        PH_PRE; MFQ(1, 1); PH_POST;
        // P5: tile-b q0; stage A-a' h0
        RDA(1, 0); RDB(1, 0);
        if (pf) STG(aBase, 0, tka + 128, 0);
        PH_PRE; MFQ(0, 0); PH_POST;
        // P6: B n2-3; stage A-a' h1
        RDB(1, 1);
        if (pf) STG(aBase, 128, tka + 128, 16384);
        PH_PRE; MFQ(0, 1); PH_POST;
        // P7: A m4-7; stage B-b' h0
        RDA(1, 1);
        if (pf) STG(bBase, 0, tkb + 128, 65536 + 32768);
        PH_PRE; MFQ(1, 0); PH_POST;
        // P8: no reads; stage B-b' h1; counted vmcnt
        if (pf) {
            STG(bBase, 128, tkb + 128, 65536 + 32768 + 16384);
            asm volatile("s_waitcnt vmcnt(4)" ::: "memory");
        }
        PH_PRE; MFQ(1, 1); PH_POST;
    }
    #undef STG
    #undef RDA
    #undef RDB
    #undef MFQ
    #undef PH_PRE
    #undef PH_POST

    // ---- epilogue (128 values/thread)
    int row0 = bm * 256 + wm * 128 + grp * 4;
    int col0 = bn * 256 + wn * 64 + l15;
#pragma unroll
    for (int m = 0; m < 8; ++m) {
#pragma unroll
        for (int n = 0; n < 4; ++n) {
            int col = col0 + n * 16;
            float bv = (EPI == 0) ? 0.f : bias[col];
#pragma unroll
            for (int r2 = 0; r2 < 4; ++r2) {
                int row = row0 + m * 16 + r2;
                size_t idx = (size_t)row * N + col;
                float val = acc[m][n][r2] + bv;
                if (EPI == 0) {
                    ((unsigned short*)Cout)[idx] = f2bf(val);
                } else if (EPI == 1) {
                    ((unsigned short*)Cout)[idx] = f2bf(val);
                } else if (EPI == 2) {
                    // gelu = x - x/(e^{z}+1),  z = 1.5957691*(x + 0.044715 x^3)
                    float t1 = val * val;
                    float t2 = fmaf(t1, 0.0713548163f, 1.5957691216f);
                    float z  = val * t2;
                    float e  = __expf(z);
                    float rr = frcp(e + 1.f);
                    float ge = val - val * rr;
                    ((unsigned short*)Cout)[idx] = f2bf(ge);
                } else {
                    ((float*)Cout)[idx] = val + bf2f(resid[idx]);
                }
            }
        }
    }
}

extern "C" void kernel_launch(void* const* d_in, const int* in_sizes, int n_in,
                              void* d_out, int out_size, void* d_ws, size_t ws_size,
                              hipStream_t stream) {
    const float* x       = (const float*)d_in[0];
    const float* w_qkv   = (const float*)d_in[1];
    const float* w_proj  = (const float*)d_in[2];
    const float* b_proj  = (const float*)d_in[3];
    const float* relb    = (const float*)d_in[4];
    const float* ln1g    = (const float*)d_in[5];
    const float* ln1b    = (const float*)d_in[6];
    const float* ln2g    = (const float*)d_in[7];
    const float* ln2b    = (const float*)d_in[8];
    const float* w_fc1   = (const float*)d_in[9];
    const float* b_fc1   = (const float*)d_in[10];
    const float* w_fc2   = (const float*)d_in[11];
    const float* b_fc2   = (const float*)d_in[12];
    float* out = (float*)d_out;

    hipFuncSetAttribute(reinterpret_cast<const void*>(&gemm8<0>),
                        hipFuncAttributeMaxDynamicSharedMemorySize, 131072);
    hipFuncSetAttribute(reinterpret_cast<const void*>(&gemm8<1>),
                        hipFuncAttributeMaxDynamicSharedMemorySize, 131072);
    hipFuncSetAttribute(reinterpret_cast<const void*>(&gemm8<2>),
                        hipFuncAttributeMaxDynamicSharedMemorySize, 131072);
    hipFuncSetAttribute(reinterpret_cast<const void*>(&gemm8<3>),
                        hipFuncAttributeMaxDynamicSharedMemorySize, 131072);

    char* w = (char*)d_ws;
    unsigned short* wT_qkv  = (unsigned short*)w; w += (size_t)1536 * 512 * 2;
    unsigned short* wT_proj = (unsigned short*)w; w += (size_t)512  * 512 * 2;
    unsigned short* wT_fc1  = (unsigned short*)w; w += (size_t)2048 * 512 * 2;
    unsigned short* wT_fc2  = (unsigned short*)w; w += (size_t)512  * 2048 * 2;
    float* biasb            = (float*)w;          w += (size_t)16 * 48 * 48 * 4;
    size_t wbytes = (size_t)(w - (char*)d_ws);

    int nchunk = 16;
    for (int c = 1; c <= 16; c *= 2) {
        size_t tokc = TOK / c;
        if (wbytes + tokc * 6144 <= ws_size) { nchunk = c; break; }
    }
    size_t tokc = TOK / nchunk;
    unsigned short* buf1 = (unsigned short*)w;
    unsigned short* buf2 = (unsigned short*)(w + tokc * 1024);
    unsigned short* buf3 = (unsigned short*)(w + tokc * 5120);

    wprep<<<(512 * 1536 + 255) / 256, 256, 0, stream>>>(w_qkv,  wT_qkv,  512, 1536);
    wprep<<<(512 * 512  + 255) / 256, 256, 0, stream>>>(w_proj, wT_proj, 512, 512);
    wprep<<<(512 * 2048 + 255) / 256, 256, 0, stream>>>(w_fc1,  wT_fc1,  512, 2048);
    wprep<<<(2048 * 512 + 255) / 256, 256, 0, stream>>>(w_fc2,  wT_fc2,  2048, 512);
    biasprep<<<(16 * 48 * 48 + 255) / 256, 256, 0, stream>>>(relb, biasb);

    int Mc = (int)tokc;
    int gm = Mc / 256;                  // M-tiles of 256
    int imgs = Mc / 9216;

    for (int c = 0; c < nchunk; ++c) {
        size_t toff = (size_t)c * tokc;
        const float* xc = x + toff * CCH;
        float* outc = out + toff * CCH;

        ln_k<<<Mc / 4, 256, 0, stream>>>(xc, ln1g, ln1b, buf1, Mc);
        gemm8<0><<<gm * 6, 512, 131072, stream>>>(buf1, wT_qkv, Mc, 1536, 512,
                                                  nullptr, nullptr, buf2);
        attn_mfma<<<imgs * 1024, 256, 0, stream>>>(buf2, biasb, buf1);
        gemm8<1><<<gm * 2, 512, 131072, stream>>>(buf1, wT_proj, Mc, 512, 512,
                                                  b_proj, nullptr, buf3);
        ln_bf<<<Mc / 4, 256, 0, stream>>>(buf3, ln2g, ln2b, buf1, Mc);
        gemm8<2><<<gm * 8, 512, 131072, stream>>>(buf1, wT_fc1, Mc, 2048, 512,
                                                  b_fc1, nullptr, buf2);
        gemm8<3><<<gm * 2, 512, 131072, stream>>>(buf2, wT_fc2, Mc, 512, 2048,
                                                  b_fc2, buf3, outc);
    }
}